// Round 1
// baseline (194.382 us; speedup 1.0000x reference)
//
#include <hip/hip_runtime.h>
#include <hip/hip_bf16.h>
#include <stdint.h>

#define N_PTS 262144
#define KOFF 27
#define CIN 64
#define COUT 64
#define EPS 1e-5f

typedef __attribute__((ext_vector_type(8))) short short8;
typedef __attribute__((ext_vector_type(4))) float f32x4;
typedef __attribute__((ext_vector_type(4))) unsigned short ushort4v;

static __device__ __forceinline__ unsigned short f32_to_bf16(float f) {
    union { float f; unsigned int u; } v; v.f = f;
    unsigned int u = v.u;
    unsigned int rounded = u + 0x7FFF + ((u >> 16) & 1);
    return (unsigned short)(rounded >> 16);
}

// ---- P0: pack weight [27][64][64] f32 -> bf16 MFMA B-fragment order ----
// layout: pw[k][s][t][lane][e]  (s = K-step of 32 cin, t = cout tile of 16)
// B[k_local = (lane>>4)*8+e][col = lane&15], cin = s*32 + k_local, cout = t*16 + col
__global__ void k_packW(const float* __restrict__ w, unsigned short* __restrict__ pw) {
    int tid = blockIdx.x * blockDim.x + threadIdx.x;
    if (tid >= KOFF * 4096) return;
    int e = tid & 7;
    int l = (tid >> 3) & 63;
    int t = (tid >> 9) & 3;
    int s = (tid >> 11) & 1;
    int k = tid >> 12;
    int cin  = s * 32 + (l >> 4) * 8 + e;
    int cout = t * 16 + (l & 15);
    pw[tid] = f32_to_bf16(w[(k * CIN + cin) * COUT + cout]);
}

// ---- P1: features f32 -> bf16, with zero pad row at index N ----
__global__ void k_feat2bf16(const float* __restrict__ feat, unsigned short* __restrict__ out) {
    int gid = blockIdx.x * blockDim.x + threadIdx.x;
    const int total4 = (N_PTS + 1) * CIN / 4;
    if (gid >= total4) return;
    int base = gid * 4;
    ushort4v o;
    if (base < N_PTS * CIN) {
        f32x4 f = *reinterpret_cast<const f32x4*>(feat + base);
        o[0] = f32_to_bf16(f[0]); o[1] = f32_to_bf16(f[1]);
        o[2] = f32_to_bf16(f[2]); o[3] = f32_to_bf16(f[3]);
    } else {
        o[0] = 0; o[1] = 0; o[2] = 0; o[3] = 0;
    }
    *reinterpret_cast<ushort4v*>(out + base) = o;
}

// ---- M: gather + MFMA GEMM. 256 thr = 4 waves, 128 rows/block (32/wave) ----
__global__ __launch_bounds__(256) void k_conv(
    const unsigned short* __restrict__ feat,   // (N+1) x 64 bf16
    const int* __restrict__ nbr,               // 27 x N
    const unsigned short* __restrict__ pw,     // packed weights
    float* __restrict__ conv_out,              // N x 64 (pre-BN)
    float* __restrict__ partials)              // nblocks x 128 (sum | sumsq)
{
    __shared__ unsigned short ldsB[4096];      // 8 KB: one k's packed W
    __shared__ float s_sum[64], s_sq[64];

    const int tid = threadIdx.x;
    const int l  = tid & 63;
    const int w  = tid >> 6;
    const int lr = l & 15;      // A row within 16 / C col within 16
    const int lg = l >> 4;      // k-group / C row group
    const int rowbase = blockIdx.x * 128 + w * 32;
    const int r0 = rowbase + lr;       // A rows, subtile 0
    const int r1 = r0 + 16;            // subtile 1
    const int lane_cin = lg * 8;

    if (tid < 64) { s_sum[tid] = 0.f; s_sq[tid] = 0.f; }

    f32x4 acc[2][4] = {};

    const short8* pwv = reinterpret_cast<const short8*>(pw);
    short8* ldsv = reinterpret_cast<short8*>(ldsB);

    for (int k = 0; k < KOFF; ++k) {
        __syncthreads();   // previous iteration's B reads done
        // stage this k's B tile (4096 shorts = 512 short8) into LDS
        short8 w0 = pwv[k * 512 + tid];
        short8 w1 = pwv[k * 512 + 256 + tid];
        ldsv[tid] = w0;
        ldsv[256 + tid] = w1;

        // gather A fragments for my two 16-row subtiles
        int i0 = nbr[k * N_PTS + r0];
        int i1 = nbr[k * N_PTS + r1];
        const short8* fr0 = reinterpret_cast<const short8*>(feat + i0 * 64 + lane_cin);
        const short8* fr1 = reinterpret_cast<const short8*>(feat + i1 * 64 + lane_cin);
        short8 a00 = fr0[0];   // s=0 (cin 0..31 slice)
        short8 a01 = fr0[4];   // s=1 (cin 32..63 slice, +32 shorts)
        short8 a10 = fr1[0];
        short8 a11 = fr1[4];

        __syncthreads();   // B staged
        #pragma unroll
        for (int s = 0; s < 2; ++s) {
            short8 a0 = s ? a01 : a00;
            short8 a1 = s ? a11 : a10;
            #pragma unroll
            for (int t = 0; t < 4; ++t) {
                short8 b = ldsv[(s * 4 + t) * 64 + l];
                acc[0][t] = __builtin_amdgcn_mfma_f32_16x16x32_bf16(a0, b, acc[0][t], 0, 0, 0);
                acc[1][t] = __builtin_amdgcn_mfma_f32_16x16x32_bf16(a1, b, acc[1][t], 0, 0, 0);
            }
        }
    }

    // epilogue: store conv (f32) + per-channel partial stats
    const int orow_base = rowbase + lg * 4;   // + m*16 + e  (C row = lg*4+e)
    #pragma unroll
    for (int t = 0; t < 4; ++t) {
        const int c = t * 16 + lr;            // C col = lane&15
        float psum = 0.f, psq = 0.f;
        #pragma unroll
        for (int m = 0; m < 2; ++m) {
            #pragma unroll
            for (int e = 0; e < 4; ++e) {
                float v = acc[m][t][e];
                conv_out[(orow_base + m * 16 + e) * 64 + c] = v;
                psum += v; psq += v * v;
            }
        }
        atomicAdd(&s_sum[c], psum);
        atomicAdd(&s_sq[c], psq);
    }
    __syncthreads();
    if (tid < 64) {
        partials[blockIdx.x * 128 + tid]      = s_sum[tid];
        partials[blockIdx.x * 128 + 64 + tid] = s_sq[tid];
    }
}

// ---- S: reduce partials -> scale/shift per channel ----
__global__ void k_stats(const float* __restrict__ partials,
                        const float* __restrict__ gamma,
                        const float* __restrict__ beta,
                        float* __restrict__ ss, int nblocks) {
    __shared__ float s_red[2];
    const int c = blockIdx.x;
    const int tid = threadIdx.x;
    if (tid < 2) s_red[tid] = 0.f;
    __syncthreads();
    float sum = 0.f, sq = 0.f;
    for (int b = tid; b < nblocks; b += blockDim.x) {
        sum += partials[b * 128 + c];
        sq  += partials[b * 128 + 64 + c];
    }
    #pragma unroll
    for (int off = 32; off > 0; off >>= 1) {
        sum += __shfl_down(sum, off, 64);
        sq  += __shfl_down(sq,  off, 64);
    }
    if ((tid & 63) == 0) { atomicAdd(&s_red[0], sum); atomicAdd(&s_red[1], sq); }
    __syncthreads();
    if (tid == 0) {
        float mean  = s_red[0] / (float)N_PTS;
        float var   = s_red[1] / (float)N_PTS - mean * mean;
        float scale = gamma[c] * rsqrtf(var + EPS);
        ss[c]      = scale;
        ss[64 + c] = beta[c] - mean * scale;
    }
}

// ---- F: in-place BN affine + ReLU on d_out ----
__global__ void k_bnrelu(float* __restrict__ out, const float* __restrict__ ss) {
    int gid = blockIdx.x * blockDim.x + threadIdx.x;   // N*64/4 threads
    int base = gid * 4;
    int c0 = base & 63;
    f32x4 v  = *reinterpret_cast<f32x4*>(out + base);
    f32x4 sc = *reinterpret_cast<const f32x4*>(ss + c0);
    f32x4 sh = *reinterpret_cast<const f32x4*>(ss + 64 + c0);
    f32x4 r;
    #pragma unroll
    for (int j = 0; j < 4; ++j) r[j] = fmaxf(v[j] * sc[j] + sh[j], 0.f);
    *reinterpret_cast<f32x4*>(out + base) = r;
}

extern "C" void kernel_launch(void* const* d_in, const int* in_sizes, int n_in,
                              void* d_out, int out_size, void* d_ws, size_t ws_size,
                              hipStream_t stream) {
    const float* features = (const float*)d_in[0];
    const int*   nbr      = (const int*)d_in[1];
    const float* weight   = (const float*)d_in[2];
    const float* gamma    = (const float*)d_in[3];
    const float* beta     = (const float*)d_in[4];
    float* out = (float*)d_out;
    char* ws = (char*)d_ws;

    // ws layout
    const size_t off_feat = 0;                                   // (N+1)*64 bf16 = 33,554,560 B
    const size_t off_pw   = 33554560;                            // 27*4096 bf16  =    221,184 B
    const size_t off_part = off_pw + 221184;                     // 2048*128 f32  =  1,048,576 B
    const size_t off_ss   = off_part + 1048576;                  // 128 f32
    unsigned short* feat16   = (unsigned short*)(ws + off_feat);
    unsigned short* pw       = (unsigned short*)(ws + off_pw);
    float*          partials = (float*)(ws + off_part);
    float*          ss       = (float*)(ws + off_ss);

    const int nblocks = N_PTS / 128;   // 2048

    k_packW<<<(KOFF * 4096 + 255) / 256, 256, 0, stream>>>(weight, pw);
    k_feat2bf16<<<((N_PTS + 1) * CIN / 4 + 255) / 256, 256, 0, stream>>>(features, feat16);
    k_conv<<<nblocks, 256, 0, stream>>>(feat16, nbr, pw, out, partials);
    k_stats<<<64, 256, 0, stream>>>(partials, gamma, beta, ss, nblocks);
    k_bnrelu<<<N_PTS * COUT / 4 / 256, 256, 0, stream>>>(out, ss);
}